// Round 22
// baseline (214.281 us; speedup 1.0000x reference)
//
#include <hip/hip_runtime.h>
#include <hip/hip_bf16.h>
#include <math.h>

// Mamba2EnhancedBlock: B=4 L=1024 D_MODEL=512, D_INNER=1024, NH=16, HEADDIM=64,
// D_STATE=64, D_CONV=4, NUM_HEADS=8 (ADH=64), D_IN_PROJ=2192, CONV_DIM=1152, D_FF=1024.
// Interface: ALL inputs float32, output float32. Internal: bf16.
// R22 = R19/R21 (best measured, 211.0us) + isolated QBLK=128 fattn (unbundles R12's
// untested half: 2 Q-tiles share each K/V staging+barrier; grid (8,32,4)=1024 blocks=4/CU).

#define L_      1024
#define DM      512
#define DSTATE  64
#define DCONV   4
#define DINNER  1024
#define NH_     16
#define DINPROJ 2192
#define CONVDIM 1152
#define ROWS    4096
#define LC      64
#define NC      16

typedef float  f32x4  __attribute__((ext_vector_type(4)));
typedef __bf16 bf16x8 __attribute__((ext_vector_type(8)));
typedef short  short8 __attribute__((ext_vector_type(8)));
using bf16 = __hip_bfloat16;

static __device__ __forceinline__ float b2f(ushort u) { return __uint_as_float((unsigned)u << 16); }
static __device__ __forceinline__ ushort f2b(float f) {
  return __builtin_bit_cast(unsigned short, __float2bfloat16(f));
}
static __device__ __forceinline__ void gload16(const void* g, void* l) {
  __builtin_amdgcn_global_load_lds((const __attribute__((address_space(1))) void*)g,
                                   (__attribute__((address_space(3))) void*)l, 16, 0, 0);
}
static __device__ __forceinline__ int swz(int row, int col) {
  return row * 64 + ((((col >> 3) ^ (row & 7)) << 3) | (col & 7));
}

// ------------------------------------------------ batched convert+transpose of ALL 6 weights
struct TcAll {
  const float* W[6];
  ushort* WT[6];
  int K[6], N[6], Nalloc[6], nbx[6], perm[6];
  int start[7];
};
__global__ __launch_bounds__(256) void tcall_k(TcAll d) {
  int bid = blockIdx.x;
  int i = 0;
  #pragma unroll
  for (int t = 1; t < 6; ++t) if (bid >= d.start[t]) i = t;
  int local = bid - d.start[i];
  int bx = (local % d.nbx[i]) * 32, by = (local / d.nbx[i]) * 32;
  const float* W = d.W[i];
  ushort* WT = d.WT[i];
  int K = d.K[i], N = d.N[i], Nalloc = d.Nalloc[i], pm = d.perm[i];
  __shared__ ushort tile[32][33];
  int tx = threadIdx.x & 31, ty = threadIdx.x >> 5;
  #pragma unroll
  for (int r = ty; r < 32; r += 8) {
    int gk = by + r, gn = bx + tx;
    tile[r][tx] = (gk < K && gn < N) ? f2b(W[(size_t)gk * N + gn]) : (ushort)0;
  }
  __syncthreads();
  #pragma unroll
  for (int r = ty; r < 32; r += 8) {
    int gn = bx + r, gk = by + tx;
    if (gn < Nalloc && gk < K) {
      int gn2 = gn;
      if (pm) gn2 = (gn < 1024) ? ((gn >> 4) * 32 + (gn & 15))
                                : (((gn - 1024) >> 4) * 32 + 16 + ((gn - 1024) & 15));
      WT[(size_t)gn2 * K + gk] = tile[tx][r];
    }
  }
}

// ------------------------------------------------ LayerNorm D=512, f32 in -> bf16 out
__global__ __launch_bounds__(256) void ln512(const float* __restrict__ in, const float* __restrict__ g,
                                             const float* __restrict__ be, bf16* __restrict__ out) {
  int row = blockIdx.x, tid = threadIdx.x;
  const float* x = in + (size_t)row * DM;
  float v0 = x[tid], v1 = x[tid + 256];
  float s = v0 + v1, sq = v0 * v0 + v1 * v1;
  __shared__ float red[4][2];
  __shared__ float bc[2];
  int lane = tid & 63, w = tid >> 6;
  #pragma unroll
  for (int o = 32; o; o >>= 1) { s += __shfl_down(s, o); sq += __shfl_down(sq, o); }
  if (lane == 0) { red[w][0] = s; red[w][1] = sq; }
  __syncthreads();
  if (tid == 0) {
    bc[0] = red[0][0] + red[1][0] + red[2][0] + red[3][0];
    bc[1] = red[0][1] + red[1][1] + red[2][1] + red[3][1];
  }
  __syncthreads();
  float mu = bc[0] * (1.f / DM);
  float var = bc[1] * (1.f / DM) - mu * mu;
  float rs = rsqrtf(var + 1e-5f);
  out[(size_t)row * DM + tid] = __float2bfloat16((v0 - mu) * rs * g[tid] + be[tid]);
  out[(size_t)row * DM + tid + 256] =
      __float2bfloat16((v1 - mu) * rs * g[tid + 256] + be[tid + 256]);
}

// ------------------------------------------------ BMxBN MFMA GEMM, BK=64, global_load_lds
// OMODE: 0 = bf16 store, 1 = GEGLU epilogue (BN=128 only), 2 = f32 add-in-place,
//        3 = f32 out = Rp + acc.   BM in {64,128}, BN in {64,128}.
template <int OMODE, int BM, int BN>
__global__ __launch_bounds__(256) void gemmT(const ushort* __restrict__ A, long lda, long sA1,
                                             const ushort* __restrict__ Bw, long ldb, long sB1,
                                             const float* __restrict__ bias,
                                             void* __restrict__ Cp, long ldc, long sC1,
                                             const float* __restrict__ Rp,
                                             int M, int N, int K, float scale) {
  constexpr int MFR = BM / 32;
  constexpr int NFR = BN / 32;
  __shared__ ushort As[BM * 64];
  __shared__ ushort Bs[BN * 64];
  const int tid = threadIdx.x;
  const int z = blockIdx.z;
  A  += (size_t)z * sA1;
  Bw += (size_t)z * sB1;
  const int m0 = blockIdx.y * BM, n0 = blockIdx.x * BN;
  const int wave = tid >> 6, lane = tid & 63;
  const int wr = wave >> 1, wc = wave & 1;
  const int frow = lane & 15, fgrp = lane >> 4;

  f32x4 acc[MFR][NFR];
  #pragma unroll
  for (int m = 0; m < MFR; ++m)
    #pragma unroll
    for (int n = 0; n < NFR; ++n) acc[m][n] = {0.f, 0.f, 0.f, 0.f};

  for (int kt = 0; kt < K; kt += 64) {
    #pragma unroll
    for (int it = 0; it < MFR; ++it) {
      int idx = it * 256 + tid;
      int row = idx >> 3, seg = idx & 7;
      gload16(A + (size_t)(m0 + row) * lda + kt + seg * 8, &As[idx * 8]);
    }
    #pragma unroll
    for (int it = 0; it < NFR; ++it) {
      int idx = it * 256 + tid;
      int row = idx >> 3, seg = idx & 7;
      gload16(Bw + (size_t)(n0 + row) * ldb + kt + seg * 8, &Bs[idx * 8]);
    }
    __syncthreads();
    #pragma unroll
    for (int kk = 0; kk < 64; kk += 32) {
      bf16x8 af[MFR], bfr[NFR];
      #pragma unroll
      for (int m = 0; m < MFR; ++m)
        af[m] = *(const bf16x8*)&As[(wr * (BM / 2) + m * 16 + frow) * 64 + kk + 8 * fgrp];
      #pragma unroll
      for (int n = 0; n < NFR; ++n)
        bfr[n] = *(const bf16x8*)&Bs[(wc * (BN / 2) + n * 16 + frow) * 64 + kk + 8 * fgrp];
      #pragma unroll
      for (int m = 0; m < MFR; ++m)
        #pragma unroll
        for (int n = 0; n < NFR; ++n)
          acc[m][n] = __builtin_amdgcn_mfma_f32_16x16x32_bf16(af[m], bfr[n], acc[m][n], 0, 0, 0);
    }
    __syncthreads();
  }

  if (OMODE == 1) {
    #pragma unroll
    for (int jp = 0; jp < NFR / 2; ++jp) {
      int oc = n0 / 2 + wc * (BN / 4) + jp * 16 + frow;
      float b1v = bias[oc], b2v = bias[1024 + oc];
      #pragma unroll
      for (int m = 0; m < MFR; ++m) {
        #pragma unroll
        for (int r = 0; r < 4; ++r) {
          int gm = m0 + wr * (BM / 2) + m * 16 + fgrp * 4 + r;
          float x1 = acc[m][jp * 2][r] + b1v;
          float x2 = acc[m][jp * 2 + 1][r] + b2v;
          float g = 0.5f * x1 * (1.f + erff(x1 * 0.70710678f));
          ((bf16*)Cp)[(size_t)gm * ldc + oc] = __float2bfloat16(g * x2);
        }
      }
    }
    return;
  }
  #pragma unroll
  for (int n = 0; n < NFR; ++n) {
    int gn = n0 + wc * (BN / 2) + n * 16 + frow;
    if (gn >= N) continue;
    float bv = bias ? bias[gn] : 0.f;
    #pragma unroll
    for (int m = 0; m < MFR; ++m) {
      #pragma unroll
      for (int r = 0; r < 4; ++r) {
        int gm = m0 + wr * (BM / 2) + m * 16 + fgrp * 4 + r;
        float v = acc[m][n][r] * scale + bv;
        size_t off = (size_t)z * sC1 + (size_t)gm * ldc + gn;
        if (OMODE == 0)      ((bf16*)Cp)[off] = __float2bfloat16(v);
        else if (OMODE == 2) ((float*)Cp)[off] += v;
        else                 ((float*)Cp)[off] = Rp[off] + v;
      }
    }
  }
}

// ------------------------------------------------ flash attention, fixed-max softmax,
// kv-split z=4, QBLK=128 (2 Q-tiles share each K/V staging). grid (L/128, B*H, 4).
__global__ __launch_bounds__(256) void fattn_k(const ushort* __restrict__ qkv,
                                               const ushort* __restrict__ VT,
                                               ushort* __restrict__ Opart,
                                               float* __restrict__ lpart) {
  const int qt = blockIdx.x, bh = blockIdx.y, z = blockIdx.z, b = bh >> 3, hh = bh & 7;
  const int tid = threadIdx.x, wave = tid >> 6, lane = tid & 63;
  const int frow = lane & 15, fgrp = lane >> 4;
  __shared__ __align__(16) ushort QP_lds[64 * 64];
  __shared__ __align__(16) ushort K_lds[2][64 * 64];
  __shared__ __align__(16) ushort V_lds[2][64 * 64];
  const int q0 = qt * 128;
  const int kv0 = z * 4;
  const int r0 = tid >> 3, r1 = r0 + 32, sg = (tid & 7) * 8;

  // stage both Q tiles through the (not yet used) K buffers
  *(short8*)&K_lds[0][swz(r0, sg)] =
      *(const short8*)(qkv + (size_t)(b * L_ + q0 + r0) * 1536 + hh * 64 + sg);
  *(short8*)&K_lds[0][swz(r1, sg)] =
      *(const short8*)(qkv + (size_t)(b * L_ + q0 + r1) * 1536 + hh * 64 + sg);
  *(short8*)&K_lds[1][swz(r0, sg)] =
      *(const short8*)(qkv + (size_t)(b * L_ + q0 + 64 + r0) * 1536 + hh * 64 + sg);
  *(short8*)&K_lds[1][swz(r1, sg)] =
      *(const short8*)(qkv + (size_t)(b * L_ + q0 + 64 + r1) * 1536 + hh * 64 + sg);
  __syncthreads();
  bf16x8 qf[2][2];
  #pragma unroll
  for (int q2 = 0; q2 < 2; ++q2) {
    qf[q2][0] = *(const bf16x8*)&K_lds[q2][swz(wave * 16 + frow, 8 * fgrp)];
    qf[q2][1] = *(const bf16x8*)&K_lds[q2][swz(wave * 16 + frow, 32 + 8 * fgrp)];
  }
  __syncthreads();

  float l_r[2][4] = {{0.f, 0.f, 0.f, 0.f}, {0.f, 0.f, 0.f, 0.f}};
  f32x4 o_acc[2][4];
  #pragma unroll
  for (int q2 = 0; q2 < 2; ++q2)
    #pragma unroll
    for (int j = 0; j < 4; ++j) o_acc[q2][j] = {0.f, 0.f, 0.f, 0.f};

  short8 kr0, kr1, vr0, vr1;
  {
    const ushort* kp = qkv + (size_t)(b * L_ + kv0 * 64) * 1536 + 512 + hh * 64;
    kr0 = *(const short8*)(kp + (size_t)r0 * 1536 + sg);
    kr1 = *(const short8*)(kp + (size_t)r1 * 1536 + sg);
    const ushort* vp = VT + (size_t)bh * 65536 + kv0 * 64;
    vr0 = *(const short8*)(vp + (size_t)r0 * 1024 + sg);
    vr1 = *(const short8*)(vp + (size_t)r1 * 1024 + sg);
  }

  for (int kv = kv0; kv < kv0 + 4; ++kv) {
    const int cur = kv & 1;
    *(short8*)&K_lds[cur][swz(r0, sg)] = kr0;
    *(short8*)&K_lds[cur][swz(r1, sg)] = kr1;
    *(short8*)&V_lds[cur][swz(r0, sg)] = vr0;
    *(short8*)&V_lds[cur][swz(r1, sg)] = vr1;
    __syncthreads();
    if (kv < kv0 + 3) {
      const ushort* kp = qkv + (size_t)(b * L_ + (kv + 1) * 64) * 1536 + 512 + hh * 64;
      kr0 = *(const short8*)(kp + (size_t)r0 * 1536 + sg);
      kr1 = *(const short8*)(kp + (size_t)r1 * 1536 + sg);
      const ushort* vp = VT + (size_t)bh * 65536 + (kv + 1) * 64;
      vr0 = *(const short8*)(vp + (size_t)r0 * 1024 + sg);
      vr1 = *(const short8*)(vp + (size_t)r1 * 1024 + sg);
    }

    #pragma unroll
    for (int q2 = 0; q2 < 2; ++q2) {
      f32x4 s[4];
      #pragma unroll
      for (int j = 0; j < 4; ++j) s[j] = {0.f, 0.f, 0.f, 0.f};
      #pragma unroll
      for (int kk = 0; kk < 2; ++kk) {
        bf16x8 a = qf[q2][kk];
        #pragma unroll
        for (int j = 0; j < 4; ++j) {
          bf16x8 bb = *(const bf16x8*)&K_lds[cur][swz(j * 16 + frow, kk * 32 + 8 * fgrp)];
          s[j] = __builtin_amdgcn_mfma_f32_16x16x32_bf16(a, bb, s[j], 0, 0, 0);
        }
      }
      #pragma unroll
      for (int r = 0; r < 4; ++r) {
        #pragma unroll
        for (int j = 0; j < 4; ++j) {
          float p = __expf(s[j][r] * 0.125f);
          s[j][r] = p;
          l_r[q2][r] += p;
        }
      }
      #pragma unroll
      for (int r = 0; r < 4; ++r)
        #pragma unroll
        for (int j = 0; j < 4; ++j)
          QP_lds[swz(wave * 16 + fgrp * 4 + r, j * 16 + frow)] = f2b(s[j][r]);
      #pragma unroll
      for (int kk = 0; kk < 2; ++kk) {
        bf16x8 pa = *(const bf16x8*)&QP_lds[swz(wave * 16 + frow, kk * 32 + 8 * fgrp)];
        #pragma unroll
        for (int j = 0; j < 4; ++j) {
          bf16x8 bb = *(const bf16x8*)&V_lds[cur][swz(j * 16 + frow, kk * 32 + 8 * fgrp)];
          o_acc[q2][j] = __builtin_amdgcn_mfma_f32_16x16x32_bf16(pa, bb, o_acc[q2][j], 0, 0, 0);
        }
      }
    }
  }
  ushort* Op = Opart + (size_t)z * ROWS * DM;
  #pragma unroll
  for (int q2 = 0; q2 < 2; ++q2) {
    #pragma unroll
    for (int r = 0; r < 4; ++r) {
      #pragma unroll
      for (int o = 1; o < 16; o <<= 1) l_r[q2][r] += __shfl_xor(l_r[q2][r], o);
      int orow = q0 + q2 * 64 + wave * 16 + fgrp * 4 + r;
      #pragma unroll
      for (int j = 0; j < 4; ++j)
        Op[(size_t)(b * L_ + orow) * DM + hh * 64 + j * 16 + frow] = f2b(o_acc[q2][j][r]);
      if (frow == 0) lpart[(size_t)z * ROWS * 8 + (size_t)(b * L_ + orow) * 8 + hh] = l_r[q2][r];
    }
  }
}

// combine: h = (O0+O1+O2+O3)/(l0+l1+l2+l3)
__global__ __launch_bounds__(256) void fcomb_k(const ushort* __restrict__ Opart,
                                               const float* __restrict__ lpart,
                                               bf16* __restrict__ Out) {
  int i = blockIdx.x * 256 + threadIdx.x;
  int row = i >> 7, c4 = (i & 127) * 4;
  int hh = c4 >> 6;
  float acc[4] = {0.f, 0.f, 0.f, 0.f};
  float l = 0.f;
  #pragma unroll
  for (int z = 0; z < 4; ++z) {
    ushort4 u = *(const ushort4*)&Opart[(size_t)z * ROWS * DM + (size_t)row * DM + c4];
    acc[0] += b2f(u.x); acc[1] += b2f(u.y); acc[2] += b2f(u.z); acc[3] += b2f(u.w);
    l += lpart[(size_t)z * ROWS * 8 + (size_t)row * 8 + hh];
  }
  float inv = 1.f / l;
  ushort4 o;
  o.x = f2b(acc[0] * inv); o.y = f2b(acc[1] * inv);
  o.z = f2b(acc[2] * inv); o.w = f2b(acc[3] * inv);
  *(ushort4*)&Out[(size_t)row * DM + c4] = o;
}

// ------------------------------------------------ causal conv4 + silu, div-free + vectorized.
__global__ __launch_bounds__(256) void convk(const ushort* __restrict__ zx, const float* __restrict__ cw,
                                             const float* __restrict__ cb, ushort* __restrict__ xbc) {
  const int rt = blockIdx.x;
  const int t = rt & (L_ - 1);
  const int tid = threadIdx.x;
  const ushort* zrow = zx + (size_t)rt * DINPROJ + DINNER;
  ushort* xrow = xbc + (size_t)rt * CONVDIM;
  for (int cc = tid * 4; cc < CONVDIM; cc += 1024) {
    float4 w0 = *(const float4*)&cw[cc * 4];
    float4 w1 = *(const float4*)&cw[cc * 4 + 4];
    float4 w2 = *(const float4*)&cw[cc * 4 + 8];
    float4 w3 = *(const float4*)&cw[cc * 4 + 12];
    float4 bias = *(const float4*)&cb[cc];
    float a0 = bias.x, a1 = bias.y, a2 = bias.z, a3 = bias.w;
    #pragma unroll
    for (int k = 0; k < DCONV; ++k) {
      int dt_ = k - 3;
      if (t + dt_ >= 0) {
        ushort4 v = *(const ushort4*)(zrow + (long)dt_ * DINPROJ + cc);
        a0 += b2f(v.x) * ((const float*)&w0)[k];
        a1 += b2f(v.y) * ((const float*)&w1)[k];
        a2 += b2f(v.z) * ((const float*)&w2)[k];
        a3 += b2f(v.w) * ((const float*)&w3)[k];
      }
    }
    ushort4 o;
    o.x = f2b(a0 / (1.f + __expf(-a0)));
    o.y = f2b(a1 / (1.f + __expf(-a1)));
    o.z = f2b(a2 / (1.f + __expf(-a2)));
    o.w = f2b(a3 / (1.f + __expf(-a3)));
    *(ushort4*)(xrow + cc) = o;
  }
}

// ================================================================ chunked scan via MFMA
__global__ __launch_bounds__(256) void scanA_k(const ushort* __restrict__ xbc,
                                               const ushort* __restrict__ zx,
                                               const float* __restrict__ dtb,
                                               const float* __restrict__ alog,
                                               ushort* __restrict__ Sbuf,
                                               float* __restrict__ Pbuf,
                                               float* __restrict__ laBuf,
                                               float* __restrict__ dtBuf) {
  const int c = blockIdx.x, bh = blockIdx.y, b = bh >> 4, hh = bh & 15;
  const int tid = threadIdx.x, wave = tid >> 6, lane = tid & 63;
  const int frow = lane & 15, fgrp = lane >> 4;
  const int t0 = c * LC;
  __shared__ __align__(16) ushort XT[64][72];
  __shared__ __align__(16) ushort BT[64][72];
  __shared__ float sw[64];

  if (tid < 64) {
    int row = b * L_ + t0 + tid;
    float v = b2f(zx[(size_t)row * DINPROJ + (DINPROJ - NH_) + hh]) + dtb[hh];
    float d = (v > 20.f) ? v : log1pf(__expf(v));
    float la = -__expf(alog[hh]) * d;
    #pragma unroll
    for (int off = 1; off < 64; off <<= 1) {
      float u = __shfl_up(la, off);
      if (tid >= off) la += u;
    }
    float la63 = __shfl(la, 63);
    sw[tid] = d * __expf(la63 - la);
    laBuf[((size_t)bh * NC + c) * 64 + tid] = la;
    dtBuf[((size_t)bh * NC + c) * 64 + tid] = d;
    if (tid == 63) Pbuf[bh * NC + c] = __expf(la);
  }
  __syncthreads();

  {
    int t = tid >> 2, ch0 = (tid & 3) * 16;
    size_t base = (size_t)(b * L_ + t0 + t) * CONVDIM;
    short8 x0 = *(const short8*)&xbc[base + hh * 64 + ch0];
    short8 x1 = *(const short8*)&xbc[base + hh * 64 + ch0 + 8];
    short8 b0 = *(const short8*)&xbc[base + DINNER + ch0];
    short8 b1 = *(const short8*)&xbc[base + DINNER + ch0 + 8];
    float wt = sw[t];
    #pragma unroll
    for (int j = 0; j < 8; ++j) {
      XT[ch0 + j][t]     = f2b(b2f((ushort)x0[j]) * wt);
      XT[ch0 + 8 + j][t] = f2b(b2f((ushort)x1[j]) * wt);
      BT[ch0 + j][t]     = (ushort)b0[j];
      BT[ch0 + 8 + j][t] = (ushort)b1[j];
    }
  }
  __syncthreads();

  f32x4 acc[4];
  #pragma unroll
  for (int j = 0; j < 4; ++j) acc[j] = {0.f, 0.f, 0.f, 0.f};
  #pragma unroll
  for (int kk = 0; kk < 2; ++kk) {
    bf16x8 a = *(const bf16x8*)&XT[wave * 16 + frow][kk * 32 + 8 * fgrp];
    #pragma unroll
    for (int j = 0; j < 4; ++j) {
      bf16x8 bb = *(const bf16x8*)&BT[j * 16 + frow][kk * 32 + 8 * fgrp];
      acc[j] = __builtin_amdgcn_mfma_f32_16x16x32_bf16(a, bb, acc[j], 0, 0, 0);
    }
  }
  ushort* Sp = Sbuf + ((size_t)bh * NC + c) * 4096;
  #pragma unroll
  for (int j = 0; j < 4; ++j)
    #pragma unroll
    for (int r = 0; r < 4; ++r)
      Sp[(wave * 16 + fgrp * 4 + r) * 64 + j * 16 + frow] = f2b(acc[j][r]);
}

// scanB: computes its own Hin = prefix-combine of Sbuf/Pbuf, then
// G=C B^T ; M[t][s]=e^{la_t-la_s} dt_s G[t][s] (s<=t) ; Y = M@X^T + e^{la_t}(C@Hin^T) + dsk*x
__global__ __launch_bounds__(256) void scanB_k(const ushort* __restrict__ xbc,
                                               const float* __restrict__ Dskip,
                                               const ushort* __restrict__ Sbuf,
                                               const float* __restrict__ Pbuf,
                                               const float* __restrict__ laBuf,
                                               const float* __restrict__ dtBuf,
                                               ushort* __restrict__ yb) {
  const int c = blockIdx.x, bh = blockIdx.y, b = bh >> 4, hh = bh & 15;
  const int tid = threadIdx.x, wave = tid >> 6, lane = tid & 63;
  const int frow = lane & 15, fgrp = lane >> 4;
  const int t0 = c * LC;
  __shared__ __align__(16) ushort C_l[64][72];
  __shared__ __align__(16) ushort BH[64][72];
  __shared__ __align__(16) ushort XT[64][72];
  __shared__ __align__(16) ushort M_l[64][72];
  __shared__ float sla[64], sdt[64];

  if (tid < 64) {
    sla[tid] = laBuf[((size_t)bh * NC + c) * 64 + tid];
    sdt[tid] = dtBuf[((size_t)bh * NC + c) * 64 + tid];
  }
  {
    int t = tid >> 2, ch0 = (tid & 3) * 16;
    size_t base = (size_t)(b * L_ + t0 + t) * CONVDIM;
    short8 c0 = *(const short8*)&xbc[base + DINNER + DSTATE + ch0];
    short8 c1 = *(const short8*)&xbc[base + DINNER + DSTATE + ch0 + 8];
    *(short8*)&C_l[t][ch0] = c0;
    *(short8*)&C_l[t][ch0 + 8] = c1;
    short8 b0 = *(const short8*)&xbc[base + DINNER + ch0];
    short8 b1 = *(const short8*)&xbc[base + DINNER + ch0 + 8];
    *(short8*)&BH[t][ch0] = b0;
    *(short8*)&BH[t][ch0 + 8] = b1;
    short8 x0 = *(const short8*)&xbc[base + hh * 64 + ch0];
    short8 x1 = *(const short8*)&xbc[base + hh * 64 + ch0 + 8];
    #pragma unroll
    for (int j = 0; j < 8; ++j) {
      XT[ch0 + j][t]     = (ushort)x0[j];
      XT[ch0 + 8 + j][t] = (ushort)x1[j];
    }
  }
  float Hreg[16];
  #pragma unroll
  for (int j = 0; j < 16; ++j) Hreg[j] = 0.f;
  {
    int p = tid >> 2, n0 = (tid & 3) * 16;
    for (int cc = 0; cc < c; ++cc) {
      const ushort* Sp = Sbuf + ((size_t)bh * NC + cc) * 4096 + p * 64 + n0;
      float P = Pbuf[bh * NC + cc];
      short8 a = *(const short8*)Sp;
      short8 bq = *(const short8*)(Sp + 8);
      #pragma unroll
      for (int j = 0; j < 8; ++j) {
        Hreg[j]     = Hreg[j]     * P + b2f((ushort)a[j]);
        Hreg[8 + j] = Hreg[8 + j] * P + b2f((ushort)bq[j]);
      }
    }
  }
  __syncthreads();

  f32x4 g[4];
  #pragma unroll
  for (int j = 0; j < 4; ++j) g[j] = {0.f, 0.f, 0.f, 0.f};
  #pragma unroll
  for (int kk = 0; kk < 2; ++kk) {
    bf16x8 a = *(const bf16x8*)&C_l[wave * 16 + frow][kk * 32 + 8 * fgrp];
    #pragma unroll
    for (int j = 0; j < 4; ++j) {
      bf16x8 bb = *(const bf16x8*)&BH[j * 16 + frow][kk * 32 + 8 * fgrp];
      g[j] = __builtin_amdgcn_mfma_f32_16x16x32_bf16(a, bb, g[j], 0, 0, 0);
    }
  }
  #pragma unroll
  for (int r = 0; r < 4; ++r) {
    int trow = wave * 16 + fgrp * 4 + r;
    float lat = sla[trow];
    #pragma unroll
    for (int j = 0; j < 4; ++j) {
      int scol = j * 16 + frow;
      float m = (scol <= trow) ? __expf(lat - sla[scol]) * sdt[scol] * g[j][r] : 0.f;
      M_l[trow][scol] = f2b(m);
    }
  }
  __syncthreads();
  {
    int p = tid >> 2, n0 = (tid & 3) * 16;
    short8 w0, w1;
    #pragma unroll
    for (int j = 0; j < 8; ++j) { w0[j] = (short)f2b(Hreg[j]); w1[j] = (short)f2b(Hreg[8 + j]); }
    *(short8*)&BH[p][n0] = w0;
    *(short8*)&BH[p][n0 + 8] = w1;
  }
  __syncthreads();

  f32x4 y1[4], y2[4];
  #pragma unroll
  for (int j = 0; j < 4; ++j) { y1[j] = {0.f, 0.f, 0.f, 0.f}; y2[j] = {0.f, 0.f, 0.f, 0.f}; }
  #pragma unroll
  for (int kk = 0; kk < 2; ++kk) {
    bf16x8 am = *(const bf16x8*)&M_l[wave * 16 + frow][kk * 32 + 8 * fgrp];
    bf16x8 ac = *(const bf16x8*)&C_l[wave * 16 + frow][kk * 32 + 8 * fgrp];
    #pragma unroll
    for (int j = 0; j < 4; ++j) {
      bf16x8 bx = *(const bf16x8*)&XT[j * 16 + frow][kk * 32 + 8 * fgrp];
      bf16x8 bhf = *(const bf16x8*)&BH[j * 16 + frow][kk * 32 + 8 * fgrp];
      y1[j] = __builtin_amdgcn_mfma_f32_16x16x32_bf16(am, bx, y1[j], 0, 0, 0);
      y2[j] = __builtin_amdgcn_mfma_f32_16x16x32_bf16(ac, bhf, y2[j], 0, 0, 0);
    }
  }
  float dsk = Dskip[hh];
  #pragma unroll
  for (int r = 0; r < 4; ++r) {
    int trow = wave * 16 + fgrp * 4 + r;
    float ea = __expf(sla[trow]);
    size_t orow = (size_t)(b * L_ + t0 + trow) * DINNER + hh * 64;
    #pragma unroll
    for (int j = 0; j < 4; ++j) {
      int pcol = j * 16 + frow;
      float y = y1[j][r] + ea * y2[j][r] + dsk * b2f(XT[pcol][trow]);
      yb[orow + pcol] = f2b(y);
    }
  }
}

// ------------------------------------------------ gated RMSNorm
__global__ __launch_bounds__(256) void grms_k(const ushort* __restrict__ yb, const ushort* __restrict__ zx,
                                              const float* __restrict__ gn, bf16* __restrict__ out) {
  int row = blockIdx.x, tid = threadIdx.x;
  const ushort* y = yb + (size_t)row * DINNER;
  const ushort* z = zx + (size_t)row * DINPROJ;
  float v[4], sq = 0.f;
  #pragma unroll
  for (int k = 0; k < 4; ++k) {
    int c = tid + k * 256;
    float zz = b2f(z[c]);
    float val = b2f(y[c]) * (zz / (1.f + __expf(-zz)));
    v[k] = val;
    sq += val * val;
  }
  __shared__ float red[4];
  __shared__ float bc;
  int lane = tid & 63, w = tid >> 6;
  #pragma unroll
  for (int o = 32; o; o >>= 1) sq += __shfl_down(sq, o);
  if (lane == 0) red[w] = sq;
  __syncthreads();
  if (tid == 0) bc = red[0] + red[1] + red[2] + red[3];
  __syncthreads();
  float rs = rsqrtf(bc * (1.f / DINNER) + 1e-5f);
  #pragma unroll
  for (int k = 0; k < 4; ++k) {
    int c = tid + k * 256;
    out[(size_t)row * DINNER + c] = __float2bfloat16(v[k] * rs * gn[c]);
  }
}

// ------------------------------------------------ V transpose -> VT[bh][64][1024]
__global__ __launch_bounds__(256) void vt_k(const ushort* __restrict__ qkv, ushort* __restrict__ VT) {
  int bh = blockIdx.z, b = bh >> 3, hh = bh & 7;
  int m0 = blockIdx.x * 32, d0 = blockIdx.y * 32;
  __shared__ ushort tile[32][33];
  int tx = threadIdx.x & 31, ty = threadIdx.x >> 5;
  #pragma unroll
  for (int r = ty; r < 32; r += 8)
    tile[r][tx] = qkv[(size_t)(b * L_ + m0 + r) * 1536 + 1024 + hh * 64 + d0 + tx];
  __syncthreads();
  #pragma unroll
  for (int r = ty; r < 32; r += 8)
    VT[(size_t)bh * 65536 + (size_t)(d0 + r) * 1024 + m0 + tx] = tile[tx][r];
}

// ================================================================ host
extern "C" void kernel_launch(void* const* d_in, const int* in_sizes, int n_in,
                              void* d_out, int out_size, void* d_ws, size_t ws_size,
                              hipStream_t stream) {
  const float* x_in = (const float*)d_in[0];
  const float* g1   = (const float*)d_in[1];
  const float* b1   = (const float*)d_in[2];
  const float* b_in = (const float*)d_in[4];
  const float* cw   = (const float*)d_in[5];
  const float* cb   = (const float*)d_in[6];
  const float* dtb  = (const float*)d_in[7];
  const float* alog = (const float*)d_in[8];
  const float* dsk  = (const float*)d_in[9];
  const float* gno  = (const float*)d_in[10];
  const float* bout = (const float*)d_in[12];
  const float* ga   = (const float*)d_in[13];
  const float* ba   = (const float*)d_in[14];
  const float* bqkv = (const float*)d_in[16];
  const float* bo   = (const float*)d_in[18];
  const float* g2   = (const float*)d_in[19];
  const float* b2   = (const float*)d_in[20];
  const float* b1f  = (const float*)d_in[22];
  const float* b2f_ = (const float*)d_in[24];

  char* ws = (char*)d_ws;
  ushort* WT_in  = (ushort*)(ws + 0);
  ushort* WT_out = (ushort*)(ws + 2359296);
  ushort* WT_qkv = (ushort*)(ws + 3407872);
  ushort* WT_o   = (ushort*)(ws + 4980736);
  ushort* WT_1   = (ushort*)(ws + 5505024);
  ushort* WT_2   = (ushort*)(ws + 7602176);
  float*  r   = (float*)(ws + 8650752);
  bf16*   h   = (bf16*)(ws + 17039360);
  ushort* zx  = (ushort*)(ws + 21233664);
  ushort* xbc = (ushort*)(ws + 39190528);
  ushort* yb  = (ushort*)(ws + 49152000);
  bf16*   hy  = (bf16*)(ws + 57540608);
  ushort* qkv = zx;
  ushort* Sbuf = (ushort*)hy;
  ushort* VT   = (ushort*)hy;
  float*  Pbuf  = (float*)h;
  float*  laBuf = (float*)((char*)h + 65536);
  float*  dtBuf = (float*)((char*)h + 327680);
  ushort* Opart = (ushort*)(ws + 39190528);      // attn-phase: bf16 [4][4096][512]
  float*  lpart = (float*)(ws + 55967744);       // f32 [4][4096][8]

  TcAll tc;
  tc.W[0] = (const float*)d_in[3];  tc.WT[0] = WT_in;  tc.K[0] = 512;  tc.N[0] = 2192; tc.Nalloc[0] = 2304; tc.nbx[0] = 72; tc.perm[0] = 0;
  tc.W[1] = (const float*)d_in[11]; tc.WT[1] = WT_out; tc.K[1] = 1024; tc.N[1] = 512;  tc.Nalloc[1] = 512;  tc.nbx[1] = 16; tc.perm[1] = 0;
  tc.W[2] = (const float*)d_in[15]; tc.WT[2] = WT_qkv; tc.K[2] = 512;  tc.N[2] = 1536; tc.Nalloc[2] = 1536; tc.nbx[2] = 48; tc.perm[2] = 0;
  tc.W[3] = (const float*)d_in[17]; tc.WT[3] = WT_o;   tc.K[3] = 512;  tc.N[3] = 512;  tc.Nalloc[3] = 512;  tc.nbx[3] = 16; tc.perm[3] = 0;
  tc.W[4] = (const float*)d_in[21]; tc.WT[4] = WT_1;   tc.K[4] = 512;  tc.N[4] = 2048; tc.Nalloc[4] = 2048; tc.nbx[4] = 64; tc.perm[4] = 1;
  tc.W[5] = (const float*)d_in[23]; tc.WT[5] = WT_2;   tc.K[5] = 1024; tc.N[5] = 512;  tc.Nalloc[5] = 512;  tc.nbx[5] = 16; tc.perm[5] = 0;
  tc.start[0] = 0;    tc.start[1] = 1152; tc.start[2] = 1664; tc.start[3] = 2432;
  tc.start[4] = 2688; tc.start[5] = 3712; tc.start[6] = 4224;
  tcall_k<<<4224, 256, 0, stream>>>(tc);

  // ---- SSM branch (residual r produced by Wout GEMM: r = x_in + ssm_out)
  ln512<<<ROWS, 256, 0, stream>>>(x_in, g1, b1, h);
  gemmT<0, 64, 128><<<dim3(18, 64, 1), 256, 0, stream>>>((const ushort*)h, 512, 0, WT_in, 512, 0,
                                                         b_in, zx, 2192, 0, nullptr,
                                                         4096, 2192, 512, 1.f);
  convk<<<ROWS, 256, 0, stream>>>(zx, cw, cb, xbc);
  scanA_k<<<dim3(NC, 64), 256, 0, stream>>>(xbc, zx, dtb, alog, Sbuf, Pbuf, laBuf, dtBuf);
  scanB_k<<<dim3(NC, 64), 256, 0, stream>>>(xbc, dsk, Sbuf, Pbuf, laBuf, dtBuf, yb);
  grms_k<<<ROWS, 256, 0, stream>>>(yb, zx, gno, hy);
  gemmT<3, 64, 64><<<dim3(8, 64, 1), 256, 0, stream>>>((const ushort*)hy, 1024, 0, WT_out, 1024, 0,
                                                       bout, r, 512, 0, x_in,
                                                       4096, 512, 1024, 1.f);
  // ---- attention branch
  ln512<<<ROWS, 256, 0, stream>>>(r, ga, ba, h);
  gemmT<0, 64, 128><<<dim3(12, 64, 1), 256, 0, stream>>>((const ushort*)h, 512, 0, WT_qkv, 512, 0,
                                                         bqkv, qkv, 1536, 0, nullptr,
                                                         4096, 1536, 512, 1.f);
  vt_k<<<dim3(32, 2, 32), 256, 0, stream>>>(qkv, (ushort*)VT);
  fattn_k<<<dim3(8, 32, 4), 256, 0, stream>>>(qkv, (const ushort*)VT, Opart, lpart);
  fcomb_k<<<2048, 256, 0, stream>>>(Opart, lpart, h);
  gemmT<2, 64, 64><<<dim3(8, 64, 1), 256, 0, stream>>>((const ushort*)h, 512, 0, WT_o, 512, 0,
                                                       bo, r, 512, 0, nullptr,
                                                       4096, 512, 512, 1.f);
  // ---- FFN branch
  ln512<<<ROWS, 256, 0, stream>>>(r, g2, b2, h);
  gemmT<1, 64, 128><<<dim3(16, 64, 1), 256, 0, stream>>>((const ushort*)h, 512, 0, WT_1, 512, 0,
                                                         b1f, hy, 1024, 0, nullptr,
                                                         4096, 2048, 512, 1.f);
  gemmT<3, 64, 64><<<dim3(8, 64, 1), 256, 0, stream>>>((const ushort*)hy, 1024, 0, WT_2, 1024, 0,
                                                       b2f_, d_out, 512, 0, r,
                                                       4096, 512, 1024, 1.f);
}

// Round 23
// 210.073 us; speedup vs baseline: 1.0200x; 1.0200x over previous
//
#include <hip/hip_runtime.h>
#include <hip/hip_bf16.h>
#include <math.h>

// Mamba2EnhancedBlock: B=4 L=1024 D_MODEL=512, D_INNER=1024, NH=16, HEADDIM=64,
// D_STATE=64, D_CONV=4, NUM_HEADS=8 (ADH=64), D_IN_PROJ=2192, CONV_DIM=1152, D_FF=1024.
// Interface: ALL inputs float32, output float32. Internal: bf16.
// FINAL = R19/R21 (best measured: 211.0 / 211.2 us; 3.3x vs 701 us correct baseline).
// Key structure: bf16 MFMA GEMMs w/ global_load_lds + occupancy-matched BN (64 for N=512
// K-heavy GEMMs at 2 blocks/CU, 128 elsewhere); Mamba2 chunked scan as MFMA (scanA/scanB,
// inter-chunk prefix folded into scanB); flash attention w/ fixed-max softmax, kv-split z=4,
// reg-prefetch dbuf, stride-64 XOR-swizzled LDS; GEGLU + residuals fused into GEMM epilogues.

#define L_      1024
#define DM      512
#define DSTATE  64
#define DCONV   4
#define DINNER  1024
#define NH_     16
#define DINPROJ 2192
#define CONVDIM 1152
#define ROWS    4096
#define LC      64
#define NC      16

typedef float  f32x4  __attribute__((ext_vector_type(4)));
typedef __bf16 bf16x8 __attribute__((ext_vector_type(8)));
typedef short  short8 __attribute__((ext_vector_type(8)));
using bf16 = __hip_bfloat16;

static __device__ __forceinline__ float b2f(ushort u) { return __uint_as_float((unsigned)u << 16); }
static __device__ __forceinline__ ushort f2b(float f) {
  return __builtin_bit_cast(unsigned short, __float2bfloat16(f));
}
static __device__ __forceinline__ void gload16(const void* g, void* l) {
  __builtin_amdgcn_global_load_lds((const __attribute__((address_space(1))) void*)g,
                                   (__attribute__((address_space(3))) void*)l, 16, 0, 0);
}
static __device__ __forceinline__ int swz(int row, int col) {
  return row * 64 + ((((col >> 3) ^ (row & 7)) << 3) | (col & 7));
}

// ------------------------------------------------ batched convert+transpose of ALL 6 weights
struct TcAll {
  const float* W[6];
  ushort* WT[6];
  int K[6], N[6], Nalloc[6], nbx[6], perm[6];
  int start[7];
};
__global__ __launch_bounds__(256) void tcall_k(TcAll d) {
  int bid = blockIdx.x;
  int i = 0;
  #pragma unroll
  for (int t = 1; t < 6; ++t) if (bid >= d.start[t]) i = t;
  int local = bid - d.start[i];
  int bx = (local % d.nbx[i]) * 32, by = (local / d.nbx[i]) * 32;
  const float* W = d.W[i];
  ushort* WT = d.WT[i];
  int K = d.K[i], N = d.N[i], Nalloc = d.Nalloc[i], pm = d.perm[i];
  __shared__ ushort tile[32][33];
  int tx = threadIdx.x & 31, ty = threadIdx.x >> 5;
  #pragma unroll
  for (int r = ty; r < 32; r += 8) {
    int gk = by + r, gn = bx + tx;
    tile[r][tx] = (gk < K && gn < N) ? f2b(W[(size_t)gk * N + gn]) : (ushort)0;
  }
  __syncthreads();
  #pragma unroll
  for (int r = ty; r < 32; r += 8) {
    int gn = bx + r, gk = by + tx;
    if (gn < Nalloc && gk < K) {
      int gn2 = gn;
      if (pm) gn2 = (gn < 1024) ? ((gn >> 4) * 32 + (gn & 15))
                                : (((gn - 1024) >> 4) * 32 + 16 + ((gn - 1024) & 15));
      WT[(size_t)gn2 * K + gk] = tile[tx][r];
    }
  }
}

// ------------------------------------------------ LayerNorm D=512, f32 in -> bf16 out
__global__ __launch_bounds__(256) void ln512(const float* __restrict__ in, const float* __restrict__ g,
                                             const float* __restrict__ be, bf16* __restrict__ out) {
  int row = blockIdx.x, tid = threadIdx.x;
  const float* x = in + (size_t)row * DM;
  float v0 = x[tid], v1 = x[tid + 256];
  float s = v0 + v1, sq = v0 * v0 + v1 * v1;
  __shared__ float red[4][2];
  __shared__ float bc[2];
  int lane = tid & 63, w = tid >> 6;
  #pragma unroll
  for (int o = 32; o; o >>= 1) { s += __shfl_down(s, o); sq += __shfl_down(sq, o); }
  if (lane == 0) { red[w][0] = s; red[w][1] = sq; }
  __syncthreads();
  if (tid == 0) {
    bc[0] = red[0][0] + red[1][0] + red[2][0] + red[3][0];
    bc[1] = red[0][1] + red[1][1] + red[2][1] + red[3][1];
  }
  __syncthreads();
  float mu = bc[0] * (1.f / DM);
  float var = bc[1] * (1.f / DM) - mu * mu;
  float rs = rsqrtf(var + 1e-5f);
  out[(size_t)row * DM + tid] = __float2bfloat16((v0 - mu) * rs * g[tid] + be[tid]);
  out[(size_t)row * DM + tid + 256] =
      __float2bfloat16((v1 - mu) * rs * g[tid + 256] + be[tid + 256]);
}

// ------------------------------------------------ BMxBN MFMA GEMM, BK=64, global_load_lds
// OMODE: 0 = bf16 store, 1 = GEGLU epilogue (BN=128 only), 2 = f32 add-in-place,
//        3 = f32 out = Rp + acc.   BM in {64,128}, BN in {64,128}.
template <int OMODE, int BM, int BN>
__global__ __launch_bounds__(256) void gemmT(const ushort* __restrict__ A, long lda, long sA1,
                                             const ushort* __restrict__ Bw, long ldb, long sB1,
                                             const float* __restrict__ bias,
                                             void* __restrict__ Cp, long ldc, long sC1,
                                             const float* __restrict__ Rp,
                                             int M, int N, int K, float scale) {
  constexpr int MFR = BM / 32;
  constexpr int NFR = BN / 32;
  __shared__ ushort As[BM * 64];
  __shared__ ushort Bs[BN * 64];
  const int tid = threadIdx.x;
  const int z = blockIdx.z;
  A  += (size_t)z * sA1;
  Bw += (size_t)z * sB1;
  const int m0 = blockIdx.y * BM, n0 = blockIdx.x * BN;
  const int wave = tid >> 6, lane = tid & 63;
  const int wr = wave >> 1, wc = wave & 1;
  const int frow = lane & 15, fgrp = lane >> 4;

  f32x4 acc[MFR][NFR];
  #pragma unroll
  for (int m = 0; m < MFR; ++m)
    #pragma unroll
    for (int n = 0; n < NFR; ++n) acc[m][n] = {0.f, 0.f, 0.f, 0.f};

  for (int kt = 0; kt < K; kt += 64) {
    #pragma unroll
    for (int it = 0; it < MFR; ++it) {
      int idx = it * 256 + tid;
      int row = idx >> 3, seg = idx & 7;
      gload16(A + (size_t)(m0 + row) * lda + kt + seg * 8, &As[idx * 8]);
    }
    #pragma unroll
    for (int it = 0; it < NFR; ++it) {
      int idx = it * 256 + tid;
      int row = idx >> 3, seg = idx & 7;
      gload16(Bw + (size_t)(n0 + row) * ldb + kt + seg * 8, &Bs[idx * 8]);
    }
    __syncthreads();
    #pragma unroll
    for (int kk = 0; kk < 64; kk += 32) {
      bf16x8 af[MFR], bfr[NFR];
      #pragma unroll
      for (int m = 0; m < MFR; ++m)
        af[m] = *(const bf16x8*)&As[(wr * (BM / 2) + m * 16 + frow) * 64 + kk + 8 * fgrp];
      #pragma unroll
      for (int n = 0; n < NFR; ++n)
        bfr[n] = *(const bf16x8*)&Bs[(wc * (BN / 2) + n * 16 + frow) * 64 + kk + 8 * fgrp];
      #pragma unroll
      for (int m = 0; m < MFR; ++m)
        #pragma unroll
        for (int n = 0; n < NFR; ++n)
          acc[m][n] = __builtin_amdgcn_mfma_f32_16x16x32_bf16(af[m], bfr[n], acc[m][n], 0, 0, 0);
    }
    __syncthreads();
  }

  if (OMODE == 1) {
    #pragma unroll
    for (int jp = 0; jp < NFR / 2; ++jp) {
      int oc = n0 / 2 + wc * (BN / 4) + jp * 16 + frow;
      float b1v = bias[oc], b2v = bias[1024 + oc];
      #pragma unroll
      for (int m = 0; m < MFR; ++m) {
        #pragma unroll
        for (int r = 0; r < 4; ++r) {
          int gm = m0 + wr * (BM / 2) + m * 16 + fgrp * 4 + r;
          float x1 = acc[m][jp * 2][r] + b1v;
          float x2 = acc[m][jp * 2 + 1][r] + b2v;
          float g = 0.5f * x1 * (1.f + erff(x1 * 0.70710678f));
          ((bf16*)Cp)[(size_t)gm * ldc + oc] = __float2bfloat16(g * x2);
        }
      }
    }
    return;
  }
  #pragma unroll
  for (int n = 0; n < NFR; ++n) {
    int gn = n0 + wc * (BN / 2) + n * 16 + frow;
    if (gn >= N) continue;
    float bv = bias ? bias[gn] : 0.f;
    #pragma unroll
    for (int m = 0; m < MFR; ++m) {
      #pragma unroll
      for (int r = 0; r < 4; ++r) {
        int gm = m0 + wr * (BM / 2) + m * 16 + fgrp * 4 + r;
        float v = acc[m][n][r] * scale + bv;
        size_t off = (size_t)z * sC1 + (size_t)gm * ldc + gn;
        if (OMODE == 0)      ((bf16*)Cp)[off] = __float2bfloat16(v);
        else if (OMODE == 2) ((float*)Cp)[off] += v;
        else                 ((float*)Cp)[off] = Rp[off] + v;
      }
    }
  }
}

// ------------------------------------------------ flash attention, fixed-max softmax, kv-split z=4.
__global__ __launch_bounds__(256) void fattn_k(const ushort* __restrict__ qkv,
                                               const ushort* __restrict__ VT,
                                               ushort* __restrict__ Opart,
                                               float* __restrict__ lpart) {
  const int qt = blockIdx.x, bh = blockIdx.y, z = blockIdx.z, b = bh >> 3, hh = bh & 7;
  const int tid = threadIdx.x, wave = tid >> 6, lane = tid & 63;
  const int frow = lane & 15, fgrp = lane >> 4;
  __shared__ __align__(16) ushort QP_lds[64 * 64];
  __shared__ __align__(16) ushort K_lds[2][64 * 64];
  __shared__ __align__(16) ushort V_lds[2][64 * 64];
  const int q0 = qt * 64;
  const int kv0 = z * 4;
  const int r0 = tid >> 3, r1 = r0 + 32, sg = (tid & 7) * 8;

  *(short8*)&QP_lds[swz(r0, sg)] =
      *(const short8*)(qkv + (size_t)(b * L_ + q0 + r0) * 1536 + hh * 64 + sg);
  *(short8*)&QP_lds[swz(r1, sg)] =
      *(const short8*)(qkv + (size_t)(b * L_ + q0 + r1) * 1536 + hh * 64 + sg);
  __syncthreads();
  bf16x8 qf[2];
  qf[0] = *(const bf16x8*)&QP_lds[swz(wave * 16 + frow, 8 * fgrp)];
  qf[1] = *(const bf16x8*)&QP_lds[swz(wave * 16 + frow, 32 + 8 * fgrp)];

  float l_r[4] = {0.f, 0.f, 0.f, 0.f};
  f32x4 o_acc[4];
  #pragma unroll
  for (int j = 0; j < 4; ++j) o_acc[j] = {0.f, 0.f, 0.f, 0.f};

  short8 kr0, kr1, vr0, vr1;
  {
    const ushort* kp = qkv + (size_t)(b * L_ + kv0 * 64) * 1536 + 512 + hh * 64;
    kr0 = *(const short8*)(kp + (size_t)r0 * 1536 + sg);
    kr1 = *(const short8*)(kp + (size_t)r1 * 1536 + sg);
    const ushort* vp = VT + (size_t)bh * 65536 + kv0 * 64;
    vr0 = *(const short8*)(vp + (size_t)r0 * 1024 + sg);
    vr1 = *(const short8*)(vp + (size_t)r1 * 1024 + sg);
  }

  for (int kv = kv0; kv < kv0 + 4; ++kv) {
    const int cur = kv & 1;
    *(short8*)&K_lds[cur][swz(r0, sg)] = kr0;
    *(short8*)&K_lds[cur][swz(r1, sg)] = kr1;
    *(short8*)&V_lds[cur][swz(r0, sg)] = vr0;
    *(short8*)&V_lds[cur][swz(r1, sg)] = vr1;
    __syncthreads();
    if (kv < kv0 + 3) {
      const ushort* kp = qkv + (size_t)(b * L_ + (kv + 1) * 64) * 1536 + 512 + hh * 64;
      kr0 = *(const short8*)(kp + (size_t)r0 * 1536 + sg);
      kr1 = *(const short8*)(kp + (size_t)r1 * 1536 + sg);
      const ushort* vp = VT + (size_t)bh * 65536 + (kv + 1) * 64;
      vr0 = *(const short8*)(vp + (size_t)r0 * 1024 + sg);
      vr1 = *(const short8*)(vp + (size_t)r1 * 1024 + sg);
    }

    f32x4 s[4];
    #pragma unroll
    for (int j = 0; j < 4; ++j) s[j] = {0.f, 0.f, 0.f, 0.f};
    #pragma unroll
    for (int kk = 0; kk < 2; ++kk) {
      bf16x8 a = qf[kk];
      #pragma unroll
      for (int j = 0; j < 4; ++j) {
        bf16x8 bb = *(const bf16x8*)&K_lds[cur][swz(j * 16 + frow, kk * 32 + 8 * fgrp)];
        s[j] = __builtin_amdgcn_mfma_f32_16x16x32_bf16(a, bb, s[j], 0, 0, 0);
      }
    }
    #pragma unroll
    for (int r = 0; r < 4; ++r) {
      #pragma unroll
      for (int j = 0; j < 4; ++j) {
        float p = __expf(s[j][r] * 0.125f);
        s[j][r] = p;
        l_r[r] += p;
      }
    }
    #pragma unroll
    for (int r = 0; r < 4; ++r)
      #pragma unroll
      for (int j = 0; j < 4; ++j)
        QP_lds[swz(wave * 16 + fgrp * 4 + r, j * 16 + frow)] = f2b(s[j][r]);
    #pragma unroll
    for (int kk = 0; kk < 2; ++kk) {
      bf16x8 pa = *(const bf16x8*)&QP_lds[swz(wave * 16 + frow, kk * 32 + 8 * fgrp)];
      #pragma unroll
      for (int j = 0; j < 4; ++j) {
        bf16x8 bb = *(const bf16x8*)&V_lds[cur][swz(j * 16 + frow, kk * 32 + 8 * fgrp)];
        o_acc[j] = __builtin_amdgcn_mfma_f32_16x16x32_bf16(pa, bb, o_acc[j], 0, 0, 0);
      }
    }
  }
  #pragma unroll
  for (int r = 0; r < 4; ++r) {
    #pragma unroll
    for (int o = 1; o < 16; o <<= 1) l_r[r] += __shfl_xor(l_r[r], o);
  }
  ushort* Op = Opart + (size_t)z * ROWS * DM;
  #pragma unroll
  for (int r = 0; r < 4; ++r) {
    int orow = q0 + wave * 16 + fgrp * 4 + r;
    #pragma unroll
    for (int j = 0; j < 4; ++j)
      Op[(size_t)(b * L_ + orow) * DM + hh * 64 + j * 16 + frow] = f2b(o_acc[j][r]);
    if (frow == 0) lpart[(size_t)z * ROWS * 8 + (size_t)(b * L_ + orow) * 8 + hh] = l_r[r];
  }
}

// combine: h = (O0+O1+O2+O3)/(l0+l1+l2+l3)
__global__ __launch_bounds__(256) void fcomb_k(const ushort* __restrict__ Opart,
                                               const float* __restrict__ lpart,
                                               bf16* __restrict__ Out) {
  int i = blockIdx.x * 256 + threadIdx.x;
  int row = i >> 7, c4 = (i & 127) * 4;
  int hh = c4 >> 6;
  float acc[4] = {0.f, 0.f, 0.f, 0.f};
  float l = 0.f;
  #pragma unroll
  for (int z = 0; z < 4; ++z) {
    ushort4 u = *(const ushort4*)&Opart[(size_t)z * ROWS * DM + (size_t)row * DM + c4];
    acc[0] += b2f(u.x); acc[1] += b2f(u.y); acc[2] += b2f(u.z); acc[3] += b2f(u.w);
    l += lpart[(size_t)z * ROWS * 8 + (size_t)row * 8 + hh];
  }
  float inv = 1.f / l;
  ushort4 o;
  o.x = f2b(acc[0] * inv); o.y = f2b(acc[1] * inv);
  o.z = f2b(acc[2] * inv); o.w = f2b(acc[3] * inv);
  *(ushort4*)&Out[(size_t)row * DM + c4] = o;
}

// ------------------------------------------------ causal conv4 + silu, div-free + vectorized.
__global__ __launch_bounds__(256) void convk(const ushort* __restrict__ zx, const float* __restrict__ cw,
                                             const float* __restrict__ cb, ushort* __restrict__ xbc) {
  const int rt = blockIdx.x;
  const int t = rt & (L_ - 1);
  const int tid = threadIdx.x;
  const ushort* zrow = zx + (size_t)rt * DINPROJ + DINNER;
  ushort* xrow = xbc + (size_t)rt * CONVDIM;
  for (int cc = tid * 4; cc < CONVDIM; cc += 1024) {
    float4 w0 = *(const float4*)&cw[cc * 4];
    float4 w1 = *(const float4*)&cw[cc * 4 + 4];
    float4 w2 = *(const float4*)&cw[cc * 4 + 8];
    float4 w3 = *(const float4*)&cw[cc * 4 + 12];
    float4 bias = *(const float4*)&cb[cc];
    float a0 = bias.x, a1 = bias.y, a2 = bias.z, a3 = bias.w;
    #pragma unroll
    for (int k = 0; k < DCONV; ++k) {
      int dt_ = k - 3;
      if (t + dt_ >= 0) {
        ushort4 v = *(const ushort4*)(zrow + (long)dt_ * DINPROJ + cc);
        a0 += b2f(v.x) * ((const float*)&w0)[k];
        a1 += b2f(v.y) * ((const float*)&w1)[k];
        a2 += b2f(v.z) * ((const float*)&w2)[k];
        a3 += b2f(v.w) * ((const float*)&w3)[k];
      }
    }
    ushort4 o;
    o.x = f2b(a0 / (1.f + __expf(-a0)));
    o.y = f2b(a1 / (1.f + __expf(-a1)));
    o.z = f2b(a2 / (1.f + __expf(-a2)));
    o.w = f2b(a3 / (1.f + __expf(-a3)));
    *(ushort4*)(xrow + cc) = o;
  }
}

// ================================================================ chunked scan via MFMA
__global__ __launch_bounds__(256) void scanA_k(const ushort* __restrict__ xbc,
                                               const ushort* __restrict__ zx,
                                               const float* __restrict__ dtb,
                                               const float* __restrict__ alog,
                                               ushort* __restrict__ Sbuf,
                                               float* __restrict__ Pbuf,
                                               float* __restrict__ laBuf,
                                               float* __restrict__ dtBuf) {
  const int c = blockIdx.x, bh = blockIdx.y, b = bh >> 4, hh = bh & 15;
  const int tid = threadIdx.x, wave = tid >> 6, lane = tid & 63;
  const int frow = lane & 15, fgrp = lane >> 4;
  const int t0 = c * LC;
  __shared__ __align__(16) ushort XT[64][72];
  __shared__ __align__(16) ushort BT[64][72];
  __shared__ float sw[64];

  if (tid < 64) {
    int row = b * L_ + t0 + tid;
    float v = b2f(zx[(size_t)row * DINPROJ + (DINPROJ - NH_) + hh]) + dtb[hh];
    float d = (v > 20.f) ? v : log1pf(__expf(v));
    float la = -__expf(alog[hh]) * d;
    #pragma unroll
    for (int off = 1; off < 64; off <<= 1) {
      float u = __shfl_up(la, off);
      if (tid >= off) la += u;
    }
    float la63 = __shfl(la, 63);
    sw[tid] = d * __expf(la63 - la);
    laBuf[((size_t)bh * NC + c) * 64 + tid] = la;
    dtBuf[((size_t)bh * NC + c) * 64 + tid] = d;
    if (tid == 63) Pbuf[bh * NC + c] = __expf(la);
  }
  __syncthreads();

  {
    int t = tid >> 2, ch0 = (tid & 3) * 16;
    size_t base = (size_t)(b * L_ + t0 + t) * CONVDIM;
    short8 x0 = *(const short8*)&xbc[base + hh * 64 + ch0];
    short8 x1 = *(const short8*)&xbc[base + hh * 64 + ch0 + 8];
    short8 b0 = *(const short8*)&xbc[base + DINNER + ch0];
    short8 b1 = *(const short8*)&xbc[base + DINNER + ch0 + 8];
    float wt = sw[t];
    #pragma unroll
    for (int j = 0; j < 8; ++j) {
      XT[ch0 + j][t]     = f2b(b2f((ushort)x0[j]) * wt);
      XT[ch0 + 8 + j][t] = f2b(b2f((ushort)x1[j]) * wt);
      BT[ch0 + j][t]     = (ushort)b0[j];
      BT[ch0 + 8 + j][t] = (ushort)b1[j];
    }
  }
  __syncthreads();

  f32x4 acc[4];
  #pragma unroll
  for (int j = 0; j < 4; ++j) acc[j] = {0.f, 0.f, 0.f, 0.f};
  #pragma unroll
  for (int kk = 0; kk < 2; ++kk) {
    bf16x8 a = *(const bf16x8*)&XT[wave * 16 + frow][kk * 32 + 8 * fgrp];
    #pragma unroll
    for (int j = 0; j < 4; ++j) {
      bf16x8 bb = *(const bf16x8*)&BT[j * 16 + frow][kk * 32 + 8 * fgrp];
      acc[j] = __builtin_amdgcn_mfma_f32_16x16x32_bf16(a, bb, acc[j], 0, 0, 0);
    }
  }
  ushort* Sp = Sbuf + ((size_t)bh * NC + c) * 4096;
  #pragma unroll
  for (int j = 0; j < 4; ++j)
    #pragma unroll
    for (int r = 0; r < 4; ++r)
      Sp[(wave * 16 + fgrp * 4 + r) * 64 + j * 16 + frow] = f2b(acc[j][r]);
}

// scanB: computes its own Hin = prefix-combine of Sbuf/Pbuf, then
// G=C B^T ; M[t][s]=e^{la_t-la_s} dt_s G[t][s] (s<=t) ; Y = M@X^T + e^{la_t}(C@Hin^T) + dsk*x
__global__ __launch_bounds__(256) void scanB_k(const ushort* __restrict__ xbc,
                                               const float* __restrict__ Dskip,
                                               const ushort* __restrict__ Sbuf,
                                               const float* __restrict__ Pbuf,
                                               const float* __restrict__ laBuf,
                                               const float* __restrict__ dtBuf,
                                               ushort* __restrict__ yb) {
  const int c = blockIdx.x, bh = blockIdx.y, b = bh >> 4, hh = bh & 15;
  const int tid = threadIdx.x, wave = tid >> 6, lane = tid & 63;
  const int frow = lane & 15, fgrp = lane >> 4;
  const int t0 = c * LC;
  __shared__ __align__(16) ushort C_l[64][72];
  __shared__ __align__(16) ushort BH[64][72];
  __shared__ __align__(16) ushort XT[64][72];
  __shared__ __align__(16) ushort M_l[64][72];
  __shared__ float sla[64], sdt[64];

  if (tid < 64) {
    sla[tid] = laBuf[((size_t)bh * NC + c) * 64 + tid];
    sdt[tid] = dtBuf[((size_t)bh * NC + c) * 64 + tid];
  }
  {
    int t = tid >> 2, ch0 = (tid & 3) * 16;
    size_t base = (size_t)(b * L_ + t0 + t) * CONVDIM;
    short8 c0 = *(const short8*)&xbc[base + DINNER + DSTATE + ch0];
    short8 c1 = *(const short8*)&xbc[base + DINNER + DSTATE + ch0 + 8];
    *(short8*)&C_l[t][ch0] = c0;
    *(short8*)&C_l[t][ch0 + 8] = c1;
    short8 b0 = *(const short8*)&xbc[base + DINNER + ch0];
    short8 b1 = *(const short8*)&xbc[base + DINNER + ch0 + 8];
    *(short8*)&BH[t][ch0] = b0;
    *(short8*)&BH[t][ch0 + 8] = b1;
    short8 x0 = *(const short8*)&xbc[base + hh * 64 + ch0];
    short8 x1 = *(const short8*)&xbc[base + hh * 64 + ch0 + 8];
    #pragma unroll
    for (int j = 0; j < 8; ++j) {
      XT[ch0 + j][t]     = (ushort)x0[j];
      XT[ch0 + 8 + j][t] = (ushort)x1[j];
    }
  }
  float Hreg[16];
  #pragma unroll
  for (int j = 0; j < 16; ++j) Hreg[j] = 0.f;
  {
    int p = tid >> 2, n0 = (tid & 3) * 16;
    for (int cc = 0; cc < c; ++cc) {
      const ushort* Sp = Sbuf + ((size_t)bh * NC + cc) * 4096 + p * 64 + n0;
      float P = Pbuf[bh * NC + cc];
      short8 a = *(const short8*)Sp;
      short8 bq = *(const short8*)(Sp + 8);
      #pragma unroll
      for (int j = 0; j < 8; ++j) {
        Hreg[j]     = Hreg[j]     * P + b2f((ushort)a[j]);
        Hreg[8 + j] = Hreg[8 + j] * P + b2f((ushort)bq[j]);
      }
    }
  }
  __syncthreads();

  f32x4 g[4];
  #pragma unroll
  for (int j = 0; j < 4; ++j) g[j] = {0.f, 0.f, 0.f, 0.f};
  #pragma unroll
  for (int kk = 0; kk < 2; ++kk) {
    bf16x8 a = *(const bf16x8*)&C_l[wave * 16 + frow][kk * 32 + 8 * fgrp];
    #pragma unroll
    for (int j = 0; j < 4; ++j) {
      bf16x8 bb = *(const bf16x8*)&BH[j * 16 + frow][kk * 32 + 8 * fgrp];
      g[j] = __builtin_amdgcn_mfma_f32_16x16x32_bf16(a, bb, g[j], 0, 0, 0);
    }
  }
  #pragma unroll
  for (int r = 0; r < 4; ++r) {
    int trow = wave * 16 + fgrp * 4 + r;
    float lat = sla[trow];
    #pragma unroll
    for (int j = 0; j < 4; ++j) {
      int scol = j * 16 + frow;
      float m = (scol <= trow) ? __expf(lat - sla[scol]) * sdt[scol] * g[j][r] : 0.f;
      M_l[trow][scol] = f2b(m);
    }
  }
  __syncthreads();
  {
    int p = tid >> 2, n0 = (tid & 3) * 16;
    short8 w0, w1;
    #pragma unroll
    for (int j = 0; j < 8; ++j) { w0[j] = (short)f2b(Hreg[j]); w1[j] = (short)f2b(Hreg[8 + j]); }
    *(short8*)&BH[p][n0] = w0;
    *(short8*)&BH[p][n0 + 8] = w1;
  }
  __syncthreads();

  f32x4 y1[4], y2[4];
  #pragma unroll
  for (int j = 0; j < 4; ++j) { y1[j] = {0.f, 0.f, 0.f, 0.f}; y2[j] = {0.f, 0.f, 0.f, 0.f}; }
  #pragma unroll
  for (int kk = 0; kk < 2; ++kk) {
    bf16x8 am = *(const bf16x8*)&M_l[wave * 16 + frow][kk * 32 + 8 * fgrp];
    bf16x8 ac = *(const bf16x8*)&C_l[wave * 16 + frow][kk * 32 + 8 * fgrp];
    #pragma unroll
    for (int j = 0; j < 4; ++j) {
      bf16x8 bx = *(const bf16x8*)&XT[j * 16 + frow][kk * 32 + 8 * fgrp];
      bf16x8 bhf = *(const bf16x8*)&BH[j * 16 + frow][kk * 32 + 8 * fgrp];
      y1[j] = __builtin_amdgcn_mfma_f32_16x16x32_bf16(am, bx, y1[j], 0, 0, 0);
      y2[j] = __builtin_amdgcn_mfma_f32_16x16x32_bf16(ac, bhf, y2[j], 0, 0, 0);
    }
  }
  float dsk = Dskip[hh];
  #pragma unroll
  for (int r = 0; r < 4; ++r) {
    int trow = wave * 16 + fgrp * 4 + r;
    float ea = __expf(sla[trow]);
    size_t orow = (size_t)(b * L_ + t0 + trow) * DINNER + hh * 64;
    #pragma unroll
    for (int j = 0; j < 4; ++j) {
      int pcol = j * 16 + frow;
      float y = y1[j][r] + ea * y2[j][r] + dsk * b2f(XT[pcol][trow]);
      yb[orow + pcol] = f2b(y);
    }
  }
}

// ------------------------------------------------ gated RMSNorm
__global__ __launch_bounds__(256) void grms_k(const ushort* __restrict__ yb, const ushort* __restrict__ zx,
                                              const float* __restrict__ gn, bf16* __restrict__ out) {
  int row = blockIdx.x, tid = threadIdx.x;
  const ushort* y = yb + (size_t)row * DINNER;
  const ushort* z = zx + (size_t)row * DINPROJ;
  float v[4], sq = 0.f;
  #pragma unroll
  for (int k = 0; k < 4; ++k) {
    int c = tid + k * 256;
    float zz = b2f(z[c]);
    float val = b2f(y[c]) * (zz / (1.f + __expf(-zz)));
    v[k] = val;
    sq += val * val;
  }
  __shared__ float red[4];
  __shared__ float bc;
  int lane = tid & 63, w = tid >> 6;
  #pragma unroll
  for (int o = 32; o; o >>= 1) sq += __shfl_down(sq, o);
  if (lane == 0) red[w] = sq;
  __syncthreads();
  if (tid == 0) bc = red[0] + red[1] + red[2] + red[3];
  __syncthreads();
  float rs = rsqrtf(bc * (1.f / DINNER) + 1e-5f);
  #pragma unroll
  for (int k = 0; k < 4; ++k) {
    int c = tid + k * 256;
    out[(size_t)row * DINNER + c] = __float2bfloat16(v[k] * rs * gn[c]);
  }
}

// ------------------------------------------------ V transpose -> VT[bh][64][1024]
__global__ __launch_bounds__(256) void vt_k(const ushort* __restrict__ qkv, ushort* __restrict__ VT) {
  int bh = blockIdx.z, b = bh >> 3, hh = bh & 7;
  int m0 = blockIdx.x * 32, d0 = blockIdx.y * 32;
  __shared__ ushort tile[32][33];
  int tx = threadIdx.x & 31, ty = threadIdx.x >> 5;
  #pragma unroll
  for (int r = ty; r < 32; r += 8)
    tile[r][tx] = qkv[(size_t)(b * L_ + m0 + r) * 1536 + 1024 + hh * 64 + d0 + tx];
  __syncthreads();
  #pragma unroll
  for (int r = ty; r < 32; r += 8)
    VT[(size_t)bh * 65536 + (size_t)(d0 + r) * 1024 + m0 + tx] = tile[tx][r];
}

// ================================================================ host
extern "C" void kernel_launch(void* const* d_in, const int* in_sizes, int n_in,
                              void* d_out, int out_size, void* d_ws, size_t ws_size,
                              hipStream_t stream) {
  const float* x_in = (const float*)d_in[0];
  const float* g1   = (const float*)d_in[1];
  const float* b1   = (const float*)d_in[2];
  const float* b_in = (const float*)d_in[4];
  const float* cw   = (const float*)d_in[5];
  const float* cb   = (const float*)d_in[6];
  const float* dtb  = (const float*)d_in[7];
  const float* alog = (const float*)d_in[8];
  const float* dsk  = (const float*)d_in[9];
  const float* gno  = (const float*)d_in[10];
  const float* bout = (const float*)d_in[12];
  const float* ga   = (const float*)d_in[13];
  const float* ba   = (const float*)d_in[14];
  const float* bqkv = (const float*)d_in[16];
  const float* bo   = (const float*)d_in[18];
  const float* g2   = (const float*)d_in[19];
  const float* b2   = (const float*)d_in[20];
  const float* b1f  = (const float*)d_in[22];
  const float* b2f_ = (const float*)d_in[24];

  char* ws = (char*)d_ws;
  ushort* WT_in  = (ushort*)(ws + 0);
  ushort* WT_out = (ushort*)(ws + 2359296);
  ushort* WT_qkv = (ushort*)(ws + 3407872);
  ushort* WT_o   = (ushort*)(ws + 4980736);
  ushort* WT_1   = (ushort*)(ws + 5505024);
  ushort* WT_2   = (ushort*)(ws + 7602176);
  float*  r   = (float*)(ws + 8650752);
  bf16*   h   = (bf16*)(ws + 17039360);
  ushort* zx  = (ushort*)(ws + 21233664);
  ushort* xbc = (ushort*)(ws + 39190528);
  ushort* yb  = (ushort*)(ws + 49152000);
  bf16*   hy  = (bf16*)(ws + 57540608);
  ushort* qkv = zx;
  ushort* Sbuf = (ushort*)hy;
  ushort* VT   = (ushort*)hy;
  float*  Pbuf  = (float*)h;
  float*  laBuf = (float*)((char*)h + 65536);
  float*  dtBuf = (float*)((char*)h + 327680);
  ushort* Opart = (ushort*)(ws + 39190528);      // attn-phase: bf16 [4][4096][512]
  float*  lpart = (float*)(ws + 55967744);       // f32 [4][4096][8]

  TcAll tc;
  tc.W[0] = (const float*)d_in[3];  tc.WT[0] = WT_in;  tc.K[0] = 512;  tc.N[0] = 2192; tc.Nalloc[0] = 2304; tc.nbx[0] = 72; tc.perm[0] = 0;
  tc.W[1] = (const float*)d_in[11]; tc.WT[1] = WT_out; tc.K[1] = 1024; tc.N[1] = 512;  tc.Nalloc[1] = 512;  tc.nbx[1] = 16; tc.perm[1] = 0;
  tc.W[2] = (const float*)d_in[15]; tc.WT[2] = WT_qkv; tc.K[2] = 512;  tc.N[2] = 1536; tc.Nalloc[2] = 1536; tc.nbx[2] = 48; tc.perm[2] = 0;
  tc.W[3] = (const float*)d_in[17]; tc.WT[3] = WT_o;   tc.K[3] = 512;  tc.N[3] = 512;  tc.Nalloc[3] = 512;  tc.nbx[3] = 16; tc.perm[3] = 0;
  tc.W[4] = (const float*)d_in[21]; tc.WT[4] = WT_1;   tc.K[4] = 512;  tc.N[4] = 2048; tc.Nalloc[4] = 2048; tc.nbx[4] = 64; tc.perm[4] = 1;
  tc.W[5] = (const float*)d_in[23]; tc.WT[5] = WT_2;   tc.K[5] = 1024; tc.N[5] = 512;  tc.Nalloc[5] = 512;  tc.nbx[5] = 16; tc.perm[5] = 0;
  tc.start[0] = 0;    tc.start[1] = 1152; tc.start[2] = 1664; tc.start[3] = 2432;
  tc.start[4] = 2688; tc.start[5] = 3712; tc.start[6] = 4224;
  tcall_k<<<4224, 256, 0, stream>>>(tc);

  // ---- SSM branch (residual r produced by Wout GEMM: r = x_in + ssm_out)
  ln512<<<ROWS, 256, 0, stream>>>(x_in, g1, b1, h);
  gemmT<0, 64, 128><<<dim3(18, 64, 1), 256, 0, stream>>>((const ushort*)h, 512, 0, WT_in, 512, 0,
                                                         b_in, zx, 2192, 0, nullptr,
                                                         4096, 2192, 512, 1.f);
  convk<<<ROWS, 256, 0, stream>>>(zx, cw, cb, xbc);
  scanA_k<<<dim3(NC, 64), 256, 0, stream>>>(xbc, zx, dtb, alog, Sbuf, Pbuf, laBuf, dtBuf);
  scanB_k<<<dim3(NC, 64), 256, 0, stream>>>(xbc, dsk, Sbuf, Pbuf, laBuf, dtBuf, yb);
  grms_k<<<ROWS, 256, 0, stream>>>(yb, zx, gno, hy);
  gemmT<3, 64, 64><<<dim3(8, 64, 1), 256, 0, stream>>>((const ushort*)hy, 1024, 0, WT_out, 1024, 0,
                                                       bout, r, 512, 0, x_in,
                                                       4096, 512, 1024, 1.f);
  // ---- attention branch
  ln512<<<ROWS, 256, 0, stream>>>(r, ga, ba, h);
  gemmT<0, 64, 128><<<dim3(12, 64, 1), 256, 0, stream>>>((const ushort*)h, 512, 0, WT_qkv, 512, 0,
                                                         bqkv, qkv, 1536, 0, nullptr,
                                                         4096, 1536, 512, 1.f);
  vt_k<<<dim3(32, 2, 32), 256, 0, stream>>>(qkv, (ushort*)VT);
  fattn_k<<<dim3(16, 32, 4), 256, 0, stream>>>(qkv, (const ushort*)VT, Opart, lpart);
  fcomb_k<<<2048, 256, 0, stream>>>(Opart, lpart, h);
  gemmT<2, 64, 64><<<dim3(8, 64, 1), 256, 0, stream>>>((const ushort*)h, 512, 0, WT_o, 512, 0,
                                                       bo, r, 512, 0, nullptr,
                                                       4096, 512, 512, 1.f);
  // ---- FFN branch
  ln512<<<ROWS, 256, 0, stream>>>(r, g2, b2, h);
  gemmT<1, 64, 128><<<dim3(16, 64, 1), 256, 0, stream>>>((const ushort*)h, 512, 0, WT_1, 512, 0,
                                                         b1f, hy, 1024, 0, nullptr,
                                                         4096, 2048, 512, 1.f);
  gemmT<3, 64, 64><<<dim3(8, 64, 1), 256, 0, stream>>>((const ushort*)hy, 1024, 0, WT_2, 1024, 0,
                                                       b2f_, d_out, 512, 0, r,
                                                       4096, 512, 1024, 1.f);
}